// Round 9
// baseline (1177.649 us; speedup 1.0000x reference)
//
#include <hip/hip_runtime.h>

// ---- problem constants ----
constexpr int NY = 384, NX = 384, S = 4, NREC = 96, NT = 600;
constexpr int K = 8;                    // timesteps per launch
constexpr int TY = 24, TX = 48;         // interior tile (asymmetric)
constexpr int LY = 56, LX = 80;         // extended tile = T + 4K
constexpr int PAD = 16;                 // = 2K global guard
constexpr int PX = NX + 2 * PAD;        // 416
constexpr int PNN = PX * PX;            // 173056
constexpr int TBX = NX / TX;            // 8
constexpr int TBY = NY / TY;            // 16  -> 512 blocks = 2/CU
constexpr int SP = 84;                  // LDS row stride (floats)
constexpr int NPAIR = (LY / 2) * (LX / 4); // 560 vertical quad-pairs
constexpr int TPB = 256;                // slots 0,1 uniform; slot2 tid<48
constexpr float D0 = 323.80102870228766f;
constexpr float HALF_DT = 0.00025f;     // 0.5*DT
constexpr float DT2 = 2.5e-7f;          // DT*DT
constexpr float C0 = -1.0f / 12.0f, C1 = 4.0f / 3.0f, C2 = -2.5f;
constexpr float INV_DX2 = 0.0625f;      // 1/DX^2 exact

// 1D PML profile, exact reference math (runs once in init)
__device__ __forceinline__ float sig1d(int d) {
    float f = (float)d;
    float l = fmaxf((20.0f - f) / 20.0f, 0.0f);
    float r = fmaxf((f - 363.0f) / 20.0f, 0.0f);
    float m = fmaxf(l, r);
    return D0 * m * m;
}

__global__ __launch_bounds__(256) void init_all(
    const float* __restrict__ vp,
    float* __restrict__ v2p, float* __restrict__ sig1)
{
    int i = blockIdx.x * 256 + threadIdx.x;
    if (i >= PNN) return;
    int py = i / PX, px = i - py * PX;
    int dy = py - PAD, dx = px - PAD;
    bool in = ((unsigned)dy < (unsigned)NY) && ((unsigned)dx < (unsigned)NX);
    float v = in ? vp[dy * NX + dx] : 0.0f;
    v2p[i] = v * v * DT2;
    if (i < PX) sig1[i] = sig1d(i - PAD);
}

__device__ __forceinline__ float4 ld4g(const float* p) { return *(const float4*)p; }
__device__ __forceinline__ void st4g(float* p, float4 v) { *(float4*)p = v; }
__device__ __forceinline__ float get4(const float4& v, int c) {
    return c == 0 ? v.x : c == 1 ? v.y : c == 2 ? v.z : v.w;
}
__device__ __forceinline__ void set4(float4& v, int c, float x) {
    if (c == 0) v.x = x; else if (c == 1) v.y = x; else if (c == 2) v.z = x; else v.w = x;
}

// reciprocal via v_rcp + 2 Newton steps (<=1 ULP)
__device__ __forceinline__ float nr_rcp(float a) {
    float r = __builtin_amdgcn_rcpf(a);
    r = r * (2.0f - a * r);
    r = r * (2.0f - a * r);
    return r;
}

__device__ __forceinline__ void coeff_quad_tab(float syv, float4 sx4,
                                               bool iny, int gx,
                                               float4& bb, float4& ia)
{
    float h0 = HALF_DT * (syv + sx4.x), h1 = HALF_DT * (syv + sx4.y);
    float h2 = HALF_DT * (syv + sx4.z), h3 = HALF_DT * (syv + sx4.w);
    bb.x = 1.0f - h0; bb.y = 1.0f - h1; bb.z = 1.0f - h2; bb.w = 1.0f - h3;
    ia.x = (iny && (unsigned)gx < (unsigned)NX)       ? nr_rcp(1.0f + h0) : 0.0f;
    ia.y = (iny && (unsigned)(gx + 1) < (unsigned)NX) ? nr_rcp(1.0f + h1) : 0.0f;
    ia.z = (iny && (unsigned)(gx + 2) < (unsigned)NX) ? nr_rcp(1.0f + h2) : 0.0f;
    ia.w = (iny && (unsigned)(gx + 3) < (unsigned)NX) ? nr_rcp(1.0f + h3) : 0.0f;
}

// 4-cell quad update. x-chain: [xm2a, xm1a, cen.x..w, xp1a, xp2a]
__device__ __forceinline__ float4 quad_update(
    float4 cen, float4 up, float4 v2, float4 bb, float4 ia,
    float4 ym2, float4 ym1, float4 yp1, float4 yp2,
    float xm2a, float xm1a, float xp1a, float xp2a)
{
    float4 r;
    float lyv, lxv, lap;
    lyv = C0 * (ym2.x + yp2.x) + C1 * (ym1.x + yp1.x) + C2 * cen.x;
    lxv = C0 * (xm2a + cen.z) + C1 * (xm1a + cen.y) + C2 * cen.x;
    lap = (lyv + lxv) * INV_DX2;
    r.x = (2.0f * cen.x - bb.x * up.x + v2.x * lap) * ia.x;
    lyv = C0 * (ym2.y + yp2.y) + C1 * (ym1.y + yp1.y) + C2 * cen.y;
    lxv = C0 * (xm1a + cen.w) + C1 * (cen.x + cen.z) + C2 * cen.y;
    lap = (lyv + lxv) * INV_DX2;
    r.y = (2.0f * cen.y - bb.y * up.y + v2.y * lap) * ia.y;
    lyv = C0 * (ym2.z + yp2.z) + C1 * (ym1.z + yp1.z) + C2 * cen.z;
    lxv = C0 * (cen.x + xp1a) + C1 * (cen.y + cen.w) + C2 * cen.z;
    lap = (lyv + lxv) * INV_DX2;
    r.z = (2.0f * cen.z - bb.z * up.z + v2.z * lap) * ia.z;
    lyv = C0 * (ym2.w + yp2.w) + C1 * (ym1.w + yp1.w) + C2 * cen.w;
    lxv = C0 * (cen.y + xp2a) + C1 * (cen.z + xp1a) + C2 * cen.w;
    lap = (lyv + lxv) * INV_DX2;
    r.w = (2.0f * cen.w - bb.w * up.w + v2.w * lap) * ia.w;
    return r;
}

// one sub-step for a vertical pair of quads (rows rl, rl+1 at cols qc4..qc4+3)
__device__ __forceinline__ void pair_step(
    const float* __restrict__ Ain, float* __restrict__ Aout,
    int m, int rl, int qc4, float aj,
    float4& cenL, float4& cenU, float4& upL, float4& upU,
    const float4& v2L, const float4& v2U, const float4& bbL, const float4& bbU,
    const float4& iaL, const float4& iaU, const float4& saL, const float4& saU)
{
    if (rl < m || rl >= LY - m || qc4 + 3 < m || qc4 >= LX - m) return;
    const int b = rl * SP + qc4;
    float4 rm2 = *(const float4*)&Ain[b - 2 * SP];
    float4 rm1 = *(const float4*)&Ain[b - SP];
    float4 rp2 = *(const float4*)&Ain[b + 2 * SP];
    float4 rp3 = *(const float4*)&Ain[b + 3 * SP];
    float2 xmL = *(const float2*)&Ain[b - 2];
    float2 xpL = *(const float2*)&Ain[b + 4];
    float2 xmU = *(const float2*)&Ain[b + SP - 2];
    float2 xpU = *(const float2*)&Ain[b + SP + 4];
    float4 rL = quad_update(cenL, upL, v2L, bbL, iaL, rm2, rm1, cenU, rp2,
                            xmL.x, xmL.y, xpL.x, xpL.y);
    float4 rU = quad_update(cenU, upU, v2U, bbU, iaU, rm1, cenL, rp2, rp3,
                            xmU.x, xmU.y, xpU.x, xpU.y);
    rL.x += aj * saL.x; rL.y += aj * saL.y; rL.z += aj * saL.z; rL.w += aj * saL.w;
    rU.x += aj * saU.x; rU.y += aj * saU.y; rU.z += aj * saU.z; rU.w += aj * saU.w;
    *(float4*)&Aout[b] = rL;
    *(float4*)&Aout[b + SP] = rU;
    upL = cenL; cenL = rL;
    upU = cenU; cenU = rU;
}

__device__ __forceinline__ void slot_setup(
    int p, int py0, int px0, int gy0, int gx0, int sly, int slx, bool has_src,
    const float* __restrict__ upIn, const float* __restrict__ ucIn,
    const float* __restrict__ v2p, const float* __restrict__ sig1,
    float* __restrict__ A0,
    int& rl, int& qc4,
    float4& cenL, float4& cenU, float4& upL, float4& upU,
    float4& v2L, float4& v2U, float4& bbL, float4& bbU,
    float4& iaL, float4& iaU, float4& saL, float4& saU)
{
    int pr = p / 20;
    qc4 = (p - pr * 20) * 4;
    rl = 2 * pr;
    int pa = (py0 + rl) * PX + px0 + qc4;
    upL = ld4g(upIn + pa);        upU = ld4g(upIn + pa + PX);
    cenL = ld4g(ucIn + pa);       cenU = ld4g(ucIn + pa + PX);
    *(float4*)&A0[rl * SP + qc4] = cenL;
    *(float4*)&A0[(rl + 1) * SP + qc4] = cenU;
    v2L = ld4g(v2p + pa);         v2U = ld4g(v2p + pa + PX);
    float syL = sig1[py0 + rl], syU = sig1[py0 + rl + 1];
    float4 sx4 = ld4g(sig1 + px0 + qc4);
    int gy = gy0 + rl, gx = gx0 + qc4;
    coeff_quad_tab(syL, sx4, (unsigned)gy < (unsigned)NY,       gx, bbL, iaL);
    coeff_quad_tab(syU, sx4, (unsigned)(gy + 1) < (unsigned)NY, gx, bbU, iaU);
    saL = make_float4(0.f, 0.f, 0.f, 0.f); saU = saL;
    if (has_src && slx >= qc4 && slx < qc4 + 4) {
        int c = slx - qc4;
        if (sly == rl)          set4(saL, c, get4(v2L, c));
        else if (sly == rl + 1) set4(saU, c, get4(v2U, c));
    }
}

__global__ __launch_bounds__(TPB) void stepK(
    float* __restrict__ ubuf,            // [S][4][PNN]
    const float* __restrict__ v2p, const float* __restrict__ sig1,
    const float* __restrict__ src_amp,   // [S, NT]
    const int* __restrict__ src_loc,     // [S, 2]
    const int* __restrict__ rec_loc,     // [S*NREC, 2]
    float* __restrict__ out,             // [S*NREC, NT]
    int t0, int pin, int pout)
{
    __shared__ __align__(16) float A0[SP * LY];
    __shared__ __align__(16) float A1[SP * LY];
    __shared__ int r_lidx[NREC];
    __shared__ int r_tout[NREC];
    __shared__ int r_cnt;

    const int tid = threadIdx.x;
    const int bx = blockIdx.x, by = blockIdx.y, s = blockIdx.z;

    const float* upIn = ubuf + (size_t)(s * 4 + pin) * PNN;
    const float* ucIn = upIn + PNN;
    float* upOut = ubuf + (size_t)(s * 4 + pout) * PNN;
    float* ucOut = upOut + PNN;

    const int py0 = by * TY;           // padded row of local (0,0)
    const int px0 = bx * TX;
    const int gy0 = py0 - PAD;         // domain coords of local (0,0)
    const int gx0 = px0 - PAD;

    const int sy = src_loc[2 * s], sx = src_loc[2 * s + 1];

    // ---- skip-zero: support after t steps is L1 ball radius 2(t-1) ----
    {
        int ddy = max(0, max(gy0 - sy, sy - (gy0 + LY - 1)));
        int ddx = max(0, max(gx0 - sx, sx - (gx0 + LX - 1)));
        if (ddy + ddx > 2 * (t0 + K) + 2) {
            if (tid < NREC) {
                int r = s * NREC + tid;
                int ry = rec_loc[2 * r], rx = rec_loc[2 * r + 1];
                if (ry >= by * TY && ry < by * TY + TY &&
                    rx >= bx * TX && rx < bx * TX + TX) {
#pragma unroll
                    for (int j = 0; j < K; ++j) out[r * NT + t0 + j] = 0.0f;
                }
            }
            return;
        }
    }

    if (tid == 0) r_cnt = 0;

    const int sly = sy - gy0, slx = sx - gx0;
    const bool has_src = ((unsigned)sly < (unsigned)LY) && ((unsigned)slx < (unsigned)LX);
    const float4 a0 = ld4g(&src_amp[s * NT + t0]);
    const float4 a1 = ld4g(&src_amp[s * NT + t0 + 4]);

    // ---- slot0: pairs 0..255, slot1: 256..511 (both uniform), slot2: 512..559 ----
    const bool act2 = (tid < NPAIR - 2 * TPB);   // tid < 48
    int rl0, qc40, rl1, qc41, rl2 = 2, qc42 = 0;
    float4 cenL0, cenU0, upL0, upU0, v2L0, v2U0, bbL0, bbU0, iaL0, iaU0, saL0, saU0;
    float4 cenL1, cenU1, upL1, upU1, v2L1, v2U1, bbL1, bbU1, iaL1, iaU1, saL1, saU1;
    float4 cenL2 = {}, cenU2 = {}, upL2 = {}, upU2 = {}, v2L2 = {}, v2U2 = {},
           bbL2 = {}, bbU2 = {}, iaL2 = {}, iaU2 = {}, saL2 = {}, saU2 = {};

    slot_setup(tid, py0, px0, gy0, gx0, sly, slx, has_src, upIn, ucIn, v2p, sig1, A0,
               rl0, qc40, cenL0, cenU0, upL0, upU0, v2L0, v2U0, bbL0, bbU0,
               iaL0, iaU0, saL0, saU0);
    slot_setup(tid + TPB, py0, px0, gy0, gx0, sly, slx, has_src, upIn, ucIn, v2p, sig1, A0,
               rl1, qc41, cenL1, cenU1, upL1, upU1, v2L1, v2U1, bbL1, bbU1,
               iaL1, iaU1, saL1, saU1);
    if (act2)
        slot_setup(tid + 2 * TPB, py0, px0, gy0, gx0, sly, slx, has_src, upIn, ucIn, v2p, sig1, A0,
                   rl2, qc42, cenL2, cenU2, upL2, upU2, v2L2, v2U2, bbL2, bbU2,
                   iaL2, iaU2, saL2, saU2);
    __syncthreads();   // covers r_cnt init + A0 writes

    // receiver ownership scan (unique interior owner)
    if (tid < NREC) {
        int r = s * NREC + tid;
        int ry = rec_loc[2 * r], rx = rec_loc[2 * r + 1];
        if (ry >= by * TY && ry < by * TY + TY && rx >= bx * TX && rx < bx * TX + TX) {
            int k = atomicAdd(&r_cnt, 1);
            r_lidx[k] = (ry - gy0) * SP + (rx - gx0);
            r_tout[k] = r * NT + t0;
        }
    }

#pragma unroll
    for (int j = 0; j < K; ++j) {
        const int m = 2 * (j + 1);
        const float* Ain = (j & 1) ? A1 : A0;
        float* Aout = (j & 1) ? A0 : A1;
        const float aj = (j == 0) ? a0.x : (j == 1) ? a0.y : (j == 2) ? a0.z :
                         (j == 3) ? a0.w : (j == 4) ? a1.x : (j == 5) ? a1.y :
                         (j == 6) ? a1.z : a1.w;
        pair_step(Ain, Aout, m, rl0, qc40, aj, cenL0, cenU0, upL0, upU0,
                  v2L0, v2U0, bbL0, bbU0, iaL0, iaU0, saL0, saU0);
        pair_step(Ain, Aout, m, rl1, qc41, aj, cenL1, cenU1, upL1, upU1,
                  v2L1, v2U1, bbL1, bbU1, iaL1, iaU1, saL1, saU1);
        if (act2)
            pair_step(Ain, Aout, m, rl2, qc42, aj, cenL2, cenU2, upL2, upU2,
                      v2L2, v2U2, bbL2, bbU2, iaL2, iaU2, saL2, saU2);
        __syncthreads();
        if (tid < r_cnt) out[r_tout[tid] + j] = Aout[r_lidx[tid]];
    }

    // ---- store interior of final pair: cen = u(t0+K), up = u(t0+K-1) ----
    if (rl0 >= PAD && rl0 < LY - PAD && qc40 >= PAD && qc40 < LX - PAD) {
        int pa = (py0 + rl0) * PX + px0 + qc40;
        st4g(ucOut + pa, cenL0);       st4g(upOut + pa, upL0);
        st4g(ucOut + pa + PX, cenU0);  st4g(upOut + pa + PX, upU0);
    }
    if (rl1 >= PAD && rl1 < LY - PAD && qc41 >= PAD && qc41 < LX - PAD) {
        int pa = (py0 + rl1) * PX + px0 + qc41;
        st4g(ucOut + pa, cenL1);       st4g(upOut + pa, upL1);
        st4g(ucOut + pa + PX, cenU1);  st4g(upOut + pa + PX, upU1);
    }
    if (act2 && rl2 >= PAD && rl2 < LY - PAD && qc42 >= PAD && qc42 < LX - PAD) {
        int pa = (py0 + rl2) * PX + px0 + qc42;
        st4g(ucOut + pa, cenL2);       st4g(upOut + pa, upL2);
        st4g(ucOut + pa + PX, cenU2);  st4g(upOut + pa + PX, upU2);
    }
}

extern "C" void kernel_launch(void* const* d_in, const int* in_sizes, int n_in,
                              void* d_out, int out_size, void* d_ws, size_t ws_size,
                              hipStream_t stream)
{
    const float* vp      = (const float*)d_in[0];
    const float* src_amp = (const float*)d_in[1];
    const int*   src_loc = (const int*)d_in[2];
    const int*   rec_loc = (const int*)d_in[3];
    float* out = (float*)d_out;

    // ws layout: v2p | sig1 | ubuf[S][4][PNN]
    float* ws = (float*)d_ws;
    float* v2p  = ws;
    float* sig1 = v2p + PNN;
    float* ubuf = sig1 + PX;

    hipMemsetAsync(ubuf, 0, (size_t)S * 4 * PNN * sizeof(float), stream);
    init_all<<<(PNN + 255) / 256, 256, 0, stream>>>(vp, v2p, sig1);

    for (int l = 0; l < NT / K; ++l) {
        int pin = (l & 1) ? 2 : 0;
        int pout = (l & 1) ? 0 : 2;
        stepK<<<dim3(TBX, TBY, S), TPB, 0, stream>>>(
            ubuf, v2p, sig1, src_amp, src_loc, rec_loc, out,
            l * K, pin, pout);
    }
}

// Round 10
// 863.859 us; speedup vs baseline: 1.3632x; 1.3632x over previous
//
#include <hip/hip_runtime.h>

// ---- problem constants ----
constexpr int NY = 384, NX = 384, S = 4, NREC = 96, NT = 600;
constexpr int K = 8;                    // timesteps per launch
constexpr int T = 48;                   // interior tile side
constexpr int L = 80;                   // extended tile side = T + 4K
constexpr int PAD = 16;                 // = 2K global guard
constexpr int PX = NX + 2 * PAD;        // 416
constexpr int PNN = PX * PX;            // 173056
constexpr int TB = NX / T;              // 8 tiles per dim
constexpr int SP = 84;                  // LDS row stride (floats)
constexpr int NPAIR = (L / 2) * (L / 4);// 800 vertical quad-pairs
constexpr int TPB = 512;                // 2 uniform slots + remainder (R4/R8 proven)
constexpr float D0 = 323.80102870228766f;
constexpr float HALF_DT = 0.00025f;     // 0.5*DT
constexpr float DT2 = 2.5e-7f;          // DT*DT
// stencil constants pre-scaled by 1/DX^2 = 1/16 (exact pow-2 scaling of
// -1/12, 4/3, -5/2: bit-identical to (lyv+lxv)*INV_DX2 of the reference)
constexpr float C0S = -1.0f / 192.0f, C1S = 1.0f / 12.0f, C2S = -0.15625f;

// 1D PML profile, exact reference math (runs once in init)
__device__ __forceinline__ float sig1d(int d) {
    float f = (float)d;
    float l = fmaxf((20.0f - f) / 20.0f, 0.0f);
    float r = fmaxf((f - 363.0f) / 20.0f, 0.0f);
    float m = fmaxf(l, r);
    return D0 * m * m;
}

__global__ __launch_bounds__(256) void init_all(
    const float* __restrict__ vp,
    float* __restrict__ v2p, float* __restrict__ sig1)
{
    int i = blockIdx.x * 256 + threadIdx.x;
    if (i >= PNN) return;
    int py = i / PX, px = i - py * PX;
    int dy = py - PAD, dx = px - PAD;
    bool in = ((unsigned)dy < (unsigned)NY) && ((unsigned)dx < (unsigned)NX);
    float v = in ? vp[dy * NX + dx] : 0.0f;
    v2p[i] = v * v * DT2;
    if (i < PX) sig1[i] = sig1d(i - PAD);
}

__device__ __forceinline__ float4 ld4g(const float* p) { return *(const float4*)p; }
__device__ __forceinline__ void st4g(float* p, float4 v) { *(float4*)p = v; }
__device__ __forceinline__ float get4(const float4& v, int c) {
    return c == 0 ? v.x : c == 1 ? v.y : c == 2 ? v.z : v.w;
}
__device__ __forceinline__ void set4(float4& v, int c, float x) {
    if (c == 0) v.x = x; else if (c == 1) v.y = x; else if (c == 2) v.z = x; else v.w = x;
}

// reciprocal via v_rcp + 2 Newton steps (<=1 ULP)
__device__ __forceinline__ float nr_rcp(float a) {
    float r = __builtin_amdgcn_rcpf(a);
    r = r * (2.0f - a * r);
    r = r * (2.0f - a * r);
    return r;
}

__device__ __forceinline__ void coeff_quad_tab(float syv, float4 sx4,
                                               bool iny, int gx,
                                               float4& bb, float4& ia)
{
    float h0 = HALF_DT * (syv + sx4.x), h1 = HALF_DT * (syv + sx4.y);
    float h2 = HALF_DT * (syv + sx4.z), h3 = HALF_DT * (syv + sx4.w);
    bb.x = 1.0f - h0; bb.y = 1.0f - h1; bb.z = 1.0f - h2; bb.w = 1.0f - h3;
    ia.x = (iny && (unsigned)gx < (unsigned)NX)       ? nr_rcp(1.0f + h0) : 0.0f;
    ia.y = (iny && (unsigned)(gx + 1) < (unsigned)NX) ? nr_rcp(1.0f + h1) : 0.0f;
    ia.z = (iny && (unsigned)(gx + 2) < (unsigned)NX) ? nr_rcp(1.0f + h2) : 0.0f;
    ia.w = (iny && (unsigned)(gx + 3) < (unsigned)NX) ? nr_rcp(1.0f + h3) : 0.0f;
}

// 4-cell quad update, stencil constants pre-scaled by 1/DX^2
__device__ __forceinline__ float4 quad_update(
    float4 cen, float4 up, float4 v2, float4 bb, float4 ia,
    float4 ym2, float4 ym1, float4 yp1, float4 yp2,
    float xm2a, float xm1a, float xp1a, float xp2a)
{
    float4 r;
    float lyv, lxv;
    lyv = C0S * (ym2.x + yp2.x) + C1S * (ym1.x + yp1.x) + C2S * cen.x;
    lxv = C0S * (xm2a + cen.z) + C1S * (xm1a + cen.y) + C2S * cen.x;
    r.x = (2.0f * cen.x - bb.x * up.x + v2.x * (lyv + lxv)) * ia.x;
    lyv = C0S * (ym2.y + yp2.y) + C1S * (ym1.y + yp1.y) + C2S * cen.y;
    lxv = C0S * (xm1a + cen.w) + C1S * (cen.x + cen.z) + C2S * cen.y;
    r.y = (2.0f * cen.y - bb.y * up.y + v2.y * (lyv + lxv)) * ia.y;
    lyv = C0S * (ym2.z + yp2.z) + C1S * (ym1.z + yp1.z) + C2S * cen.z;
    lxv = C0S * (cen.x + xp1a) + C1S * (cen.y + cen.w) + C2S * cen.z;
    r.z = (2.0f * cen.z - bb.z * up.z + v2.z * (lyv + lxv)) * ia.z;
    lyv = C0S * (ym2.w + yp2.w) + C1S * (ym1.w + yp1.w) + C2S * cen.w;
    lxv = C0S * (cen.y + xp2a) + C1S * (cen.z + xp1a) + C2S * cen.w;
    r.w = (2.0f * cen.w - bb.w * up.w + v2.w * (lyv + lxv)) * ia.w;
    return r;
}

// one sub-step for a vertical pair of quads (rows rl, rl+1 at cols qc4..qc4+3)
__device__ __forceinline__ void pair_step(
    const float* __restrict__ Ain, float* __restrict__ Aout,
    int m, int rl, int qc4, float aj, bool srcblk,
    float4& cenL, float4& cenU, float4& upL, float4& upU,
    const float4& v2L, const float4& v2U, const float4& bbL, const float4& bbU,
    const float4& iaL, const float4& iaU, const float4& saL, const float4& saU)
{
    if (rl < m || rl >= L - m || qc4 + 3 < m || qc4 >= L - m) return;
    const int b = rl * SP + qc4;
    float4 rm2 = *(const float4*)&Ain[b - 2 * SP];
    float4 rm1 = *(const float4*)&Ain[b - SP];
    float4 rp2 = *(const float4*)&Ain[b + 2 * SP];
    float4 rp3 = *(const float4*)&Ain[b + 3 * SP];
    float2 xmL = *(const float2*)&Ain[b - 2];
    float2 xpL = *(const float2*)&Ain[b + 4];
    float2 xmU = *(const float2*)&Ain[b + SP - 2];
    float2 xpU = *(const float2*)&Ain[b + SP + 4];
    float4 rL = quad_update(cenL, upL, v2L, bbL, iaL, rm2, rm1, cenU, rp2,
                            xmL.x, xmL.y, xpL.x, xpL.y);
    float4 rU = quad_update(cenU, upU, v2U, bbU, iaU, rm1, cenL, rp2, rp3,
                            xmU.x, xmU.y, xpU.x, xpU.y);
    if (srcblk) {   // block-uniform: only the source-owning block pays these FMAs
        rL.x += aj * saL.x; rL.y += aj * saL.y; rL.z += aj * saL.z; rL.w += aj * saL.w;
        rU.x += aj * saU.x; rU.y += aj * saU.y; rU.z += aj * saU.z; rU.w += aj * saU.w;
    }
    *(float4*)&Aout[b] = rL;
    *(float4*)&Aout[b + SP] = rU;
    upL = cenL; cenL = rL;
    upU = cenU; cenU = rU;
}

__device__ __forceinline__ void slot_setup(
    int p, int py0, int px0, int gy0, int gx0, int sly, int slx, bool has_src,
    const float* __restrict__ upIn, const float* __restrict__ ucIn,
    const float* __restrict__ v2p, const float* __restrict__ sig1,
    float* __restrict__ A0,
    int& rl, int& qc4,
    float4& cenL, float4& cenU, float4& upL, float4& upU,
    float4& v2L, float4& v2U, float4& bbL, float4& bbU,
    float4& iaL, float4& iaU, float4& saL, float4& saU)
{
    int pr = p / 20;
    qc4 = (p - pr * 20) * 4;
    rl = 2 * pr;
    int pa = (py0 + rl) * PX + px0 + qc4;
    upL = ld4g(upIn + pa);        upU = ld4g(upIn + pa + PX);
    cenL = ld4g(ucIn + pa);       cenU = ld4g(ucIn + pa + PX);
    *(float4*)&A0[rl * SP + qc4] = cenL;
    *(float4*)&A0[(rl + 1) * SP + qc4] = cenU;
    v2L = ld4g(v2p + pa);         v2U = ld4g(v2p + pa + PX);
    float syL = sig1[py0 + rl], syU = sig1[py0 + rl + 1];
    float4 sx4 = ld4g(sig1 + px0 + qc4);
    int gy = gy0 + rl, gx = gx0 + qc4;
    coeff_quad_tab(syL, sx4, (unsigned)gy < (unsigned)NY,       gx, bbL, iaL);
    coeff_quad_tab(syU, sx4, (unsigned)(gy + 1) < (unsigned)NY, gx, bbU, iaU);
    saL = make_float4(0.f, 0.f, 0.f, 0.f); saU = saL;
    if (has_src && slx >= qc4 && slx < qc4 + 4) {
        int c = slx - qc4;
        if (sly == rl)          set4(saL, c, get4(v2L, c));
        else if (sly == rl + 1) set4(saU, c, get4(v2U, c));
    }
}

__global__ __launch_bounds__(TPB) void stepK(
    float* __restrict__ ubuf,            // [S][4][PNN]
    const float* __restrict__ v2p, const float* __restrict__ sig1,
    const float* __restrict__ src_amp,   // [S, NT]
    const int* __restrict__ src_loc,     // [S, 2]
    const int* __restrict__ rec_loc,     // [S*NREC, 2]
    float* __restrict__ out,             // [S*NREC, NT]
    int t0, int pin, int pout)
{
    __shared__ __align__(16) float A0[SP * L];
    __shared__ __align__(16) float A1[SP * L];
    __shared__ float r_samp[NREC * K];   // receiver samples, flushed at end
    __shared__ int r_lidx[NREC];
    __shared__ int r_tout[NREC];
    __shared__ int r_cnt;

    const int tid = threadIdx.x;
    const int bx = blockIdx.x, by = blockIdx.y, s = blockIdx.z;

    const float* upIn = ubuf + (size_t)(s * 4 + pin) * PNN;
    const float* ucIn = upIn + PNN;
    float* upOut = ubuf + (size_t)(s * 4 + pout) * PNN;
    float* ucOut = upOut + PNN;

    const int py0 = by * T;            // padded row of local (0,0)
    const int px0 = bx * T;
    const int gy0 = py0 - PAD;         // domain coords of local (0,0)
    const int gx0 = px0 - PAD;

    const int sy = src_loc[2 * s], sx = src_loc[2 * s + 1];

    // ---- skip-zero: support after t steps is L1 ball radius 2(t-1) ----
    {
        int ddy = max(0, max(gy0 - sy, sy - (gy0 + L - 1)));
        int ddx = max(0, max(gx0 - sx, sx - (gx0 + L - 1)));
        if (ddy + ddx > 2 * (t0 + K) + 2) {
            if (tid < NREC) {
                int r = s * NREC + tid;
                int ry = rec_loc[2 * r], rx = rec_loc[2 * r + 1];
                if (ry >= by * T && ry < by * T + T &&
                    rx >= bx * T && rx < bx * T + T) {
#pragma unroll
                    for (int j = 0; j < K; ++j) out[r * NT + t0 + j] = 0.0f;
                }
            }
            return;
        }
    }

    if (tid == 0) r_cnt = 0;

    const int sly = sy - gy0, slx = sx - gx0;
    const bool has_src = ((unsigned)sly < (unsigned)L) && ((unsigned)slx < (unsigned)L);
    const float4 a0 = ld4g(&src_amp[s * NT + t0]);
    const float4 a1 = ld4g(&src_amp[s * NT + t0 + 4]);

    // ---- slot 0 (pairs 0..511) and slot 1 (pairs 512..799, tid<288) ----
    const bool act1 = (tid < NPAIR - TPB);
    int rl0, qc40, rl1 = 2, qc41 = 0;
    float4 cenL0, cenU0, upL0, upU0, v2L0, v2U0, bbL0, bbU0, iaL0, iaU0, saL0, saU0;
    float4 cenL1 = {}, cenU1 = {}, upL1 = {}, upU1 = {}, v2L1 = {}, v2U1 = {},
           bbL1 = {}, bbU1 = {}, iaL1 = {}, iaU1 = {}, saL1 = {}, saU1 = {};

    slot_setup(tid, py0, px0, gy0, gx0, sly, slx, has_src, upIn, ucIn, v2p, sig1, A0,
               rl0, qc40, cenL0, cenU0, upL0, upU0, v2L0, v2U0, bbL0, bbU0,
               iaL0, iaU0, saL0, saU0);
    if (act1)
        slot_setup(tid + TPB, py0, px0, gy0, gx0, sly, slx, has_src, upIn, ucIn, v2p, sig1, A0,
                   rl1, qc41, cenL1, cenU1, upL1, upU1, v2L1, v2U1, bbL1, bbU1,
                   iaL1, iaU1, saL1, saU1);
    __syncthreads();   // covers r_cnt init + A0 writes

    // receiver ownership scan (unique interior owner)
    if (tid < NREC) {
        int r = s * NREC + tid;
        int ry = rec_loc[2 * r], rx = rec_loc[2 * r + 1];
        if (ry >= by * T && ry < by * T + T && rx >= bx * T && rx < bx * T + T) {
            int k = atomicAdd(&r_cnt, 1);
            r_lidx[k] = (ry - gy0) * SP + (rx - gx0);
            r_tout[k] = r * NT + t0;
        }
    }

#pragma unroll
    for (int j = 0; j < K; ++j) {
        const int m = 2 * (j + 1);
        const float* Ain = (j & 1) ? A1 : A0;
        float* Aout = (j & 1) ? A0 : A1;
        const float aj = (j == 0) ? a0.x : (j == 1) ? a0.y : (j == 2) ? a0.z :
                         (j == 3) ? a0.w : (j == 4) ? a1.x : (j == 5) ? a1.y :
                         (j == 6) ? a1.z : a1.w;
        pair_step(Ain, Aout, m, rl0, qc40, aj, has_src, cenL0, cenU0, upL0, upU0,
                  v2L0, v2U0, bbL0, bbU0, iaL0, iaU0, saL0, saU0);
        if (act1)
            pair_step(Ain, Aout, m, rl1, qc41, aj, has_src, cenL1, cenU1, upL1, upU1,
                      v2L1, v2U1, bbL1, bbU1, iaL1, iaU1, saL1, saU1);
        __syncthreads();
        // capture receiver samples into LDS (no global store in the hot loop)
        if (tid < r_cnt) r_samp[tid * K + j] = Aout[r_lidx[tid]];
    }

    // ---- flush receiver samples ----
    if (tid < r_cnt) {
        int o = r_tout[tid];
#pragma unroll
        for (int j = 0; j < K; ++j) out[o + j] = r_samp[tid * K + j];
    }

    // ---- store interior of final pair: cen = u(t0+K), up = u(t0+K-1) ----
    if (rl0 >= PAD && rl0 < L - PAD && qc40 >= PAD && qc40 < L - PAD) {
        int pa = (py0 + rl0) * PX + px0 + qc40;
        st4g(ucOut + pa, cenL0);       st4g(upOut + pa, upL0);
        st4g(ucOut + pa + PX, cenU0);  st4g(upOut + pa + PX, upU0);
    }
    if (act1 && rl1 >= PAD && rl1 < L - PAD && qc41 >= PAD && qc41 < L - PAD) {
        int pa = (py0 + rl1) * PX + px0 + qc41;
        st4g(ucOut + pa, cenL1);       st4g(upOut + pa, upL1);
        st4g(ucOut + pa + PX, cenU1);  st4g(upOut + pa + PX, upU1);
    }
}

extern "C" void kernel_launch(void* const* d_in, const int* in_sizes, int n_in,
                              void* d_out, int out_size, void* d_ws, size_t ws_size,
                              hipStream_t stream)
{
    const float* vp      = (const float*)d_in[0];
    const float* src_amp = (const float*)d_in[1];
    const int*   src_loc = (const int*)d_in[2];
    const int*   rec_loc = (const int*)d_in[3];
    float* out = (float*)d_out;

    // ws layout: v2p | sig1 | ubuf[S][4][PNN]
    float* ws = (float*)d_ws;
    float* v2p  = ws;
    float* sig1 = v2p + PNN;
    float* ubuf = sig1 + PX;

    hipMemsetAsync(ubuf, 0, (size_t)S * 4 * PNN * sizeof(float), stream);
    init_all<<<(PNN + 255) / 256, 256, 0, stream>>>(vp, v2p, sig1);

    for (int l = 0; l < NT / K; ++l) {
        int pin = (l & 1) ? 2 : 0;
        int pout = (l & 1) ? 0 : 2;
        stepK<<<dim3(TB, TB, S), TPB, 0, stream>>>(
            ubuf, v2p, sig1, src_amp, src_loc, rec_loc, out,
            l * K, pin, pout);
    }
}